// Round 1
// baseline (613.026 us; speedup 1.0000x reference)
//
#include <hip/hip_runtime.h>
#include <math.h>

// Problem constants
// x: [4][4096][2048] f32, importance: [4][4096] f32, W: [2048][64] f32,
// b: [64] f32, neuron_emb: [4096][64] f32
// out: [4][5120] f32  (wC 2048 | wQ 1024 | wK 1024 (==wQ) | wV 1024)
#define N_ROWS 16384   // B*S
#define N_TOT  4096
#define D_IN   2048
#define DS_    64

// ---------------------------------------------------------------------------
// K0: normalize neuron embeddings (one wave per row of 64)
__global__ __launch_bounds__(256) void k_norm(const float* __restrict__ emb,
                                              float* __restrict__ embn) {
    int gid  = blockIdx.x * 256 + threadIdx.x;
    int row  = gid >> 6;
    int lane = gid & 63;
    float v  = emb[row * 64 + lane];
    float ss = v * v;
#pragma unroll
    for (int m = 32; m >= 1; m >>= 1) ss += __shfl_xor(ss, m);
    embn[row * 64 + lane] = v / sqrtf(ss);
}

// ---------------------------------------------------------------------------
// K1: h = x @ W + b   (16384x2048 @ 2048x64), fp32 vector GEMM
// block=256, tile 64 rows x 64 cols, BK=32
__global__ __launch_bounds__(256) void k_hgemm(const float* __restrict__ x,
                                               const float* __restrict__ W,
                                               const float* __restrict__ bias,
                                               float* __restrict__ h) {
    __shared__ float xs[32][64];  // [k][row]
    __shared__ float ws[32][64];  // [k][col]
    int t    = threadIdx.x;
    int row0 = blockIdx.x * 64;
    int lr   = t >> 2;            // 0..63 staging row
    int kq   = (t & 3) * 8;       // staging k offset
    int kw   = t >> 3;            // 0..31 W staging k
    int cq   = (t & 7) * 8;       // W staging col offset
    int tr   = t >> 4;            // 0..15 -> rows tr*4..+3
    int tc   = t & 15;            // cols tc*4..+3
    float acc[4][4] = {};
    for (int k0 = 0; k0 < D_IN; k0 += 32) {
        const float* xp = x + (size_t)(row0 + lr) * D_IN + k0 + kq;
        float4 a  = *(const float4*)xp;
        float4 c  = *(const float4*)(xp + 4);
        const float* wp = W + (size_t)(k0 + kw) * 64 + cq;
        float4 w0 = *(const float4*)wp;
        float4 w1 = *(const float4*)(wp + 4);
        __syncthreads();  // previous iter's reads done before overwrite
        {
            float av[8] = {a.x, a.y, a.z, a.w, c.x, c.y, c.z, c.w};
#pragma unroll
            for (int q = 0; q < 8; ++q) xs[kq + q][lr] = av[q];
        }
        *(float4*)&ws[kw][cq]     = w0;
        *(float4*)&ws[kw][cq + 4] = w1;
        __syncthreads();
#pragma unroll 8
        for (int k = 0; k < 32; ++k) {
            float4 av4 = *(const float4*)&xs[k][tr * 4];
            float4 bv4 = *(const float4*)&ws[k][tc * 4];
            float aa[4] = {av4.x, av4.y, av4.z, av4.w};
            float bb[4] = {bv4.x, bv4.y, bv4.z, bv4.w};
#pragma unroll
            for (int i = 0; i < 4; ++i)
#pragma unroll
                for (int j = 0; j < 4; ++j) acc[i][j] += aa[i] * bb[j];
        }
    }
    float4 bb4 = *(const float4*)&bias[tc * 4];
    float bs[4] = {bb4.x, bb4.y, bb4.z, bb4.w};
#pragma unroll
    for (int i = 0; i < 4; ++i) {
        int row = row0 + tr * 4 + i;
        float4 o;
        o.x = acc[i][0] + bs[0];
        o.y = acc[i][1] + bs[1];
        o.z = acc[i][2] + bs[2];
        o.w = acc[i][3] + bs[3];
        *(float4*)&h[(size_t)row * 64 + tc * 4] = o;
    }
}

// ---------------------------------------------------------------------------
// K2: per-row softmax denominators per segment -> coef = importance / Z
// block=256, 32 rows/block, neuron chunks of 128 staged in LDS
__global__ __launch_bounds__(256) void k_zpass(const float* __restrict__ h,
                                               const float* __restrict__ embn,
                                               const float* __restrict__ imp,
                                               float* __restrict__ coefC,
                                               float* __restrict__ coefQK,
                                               float* __restrict__ coefV) {
    __shared__ float hs[64][32];    // [k][row]
    __shared__ float es[64][128];   // [k][neuron]
    int t    = threadIdx.x;
    int row0 = blockIdx.x * 32;
    {
        int r = t >> 3, k0 = (t & 7) * 8;
        const float* hp = h + (size_t)(row0 + r) * 64 + k0;
        float4 a = *(const float4*)hp;
        float4 c = *(const float4*)(hp + 4);
        float av[8] = {a.x, a.y, a.z, a.w, c.x, c.y, c.z, c.w};
#pragma unroll
        for (int q = 0; q < 8; ++q) hs[k0 + q][r] = av[q];
    }
    int tr = t >> 5;   // 0..7 -> rows tr*4..+3
    int tn = t & 31;   // neurons tn*4..+3 in chunk
    const int segB[4] = {0, 2048, 3072, 4096};
    for (int sg = 0; sg < 3; ++sg) {
        float s[4] = {0.f, 0.f, 0.f, 0.f};
        for (int nb = segB[sg]; nb < segB[sg + 1]; nb += 128) {
            __syncthreads();
            {
                int n = t >> 1, k0 = (t & 1) * 32;
                const float* ep = embn + (size_t)(nb + n) * 64 + k0;
#pragma unroll
                for (int q = 0; q < 8; ++q) {
                    float4 e = *(const float4*)(ep + q * 4);
                    int k = k0 + q * 4;
                    es[k + 0][n] = e.x; es[k + 1][n] = e.y;
                    es[k + 2][n] = e.z; es[k + 3][n] = e.w;
                }
            }
            __syncthreads();
            float l[4][4] = {};
#pragma unroll 8
            for (int k = 0; k < 64; ++k) {
                float4 a4 = *(const float4*)&hs[k][tr * 4];
                float4 e4 = *(const float4*)&es[k][tn * 4];
                float aa[4] = {a4.x, a4.y, a4.z, a4.w};
                float ee[4] = {e4.x, e4.y, e4.z, e4.w};
#pragma unroll
                for (int i = 0; i < 4; ++i)
#pragma unroll
                    for (int j = 0; j < 4; ++j) l[i][j] += aa[i] * ee[j];
            }
#pragma unroll
            for (int i = 0; i < 4; ++i)
                s[i] += __expf(l[i][0]) + __expf(l[i][1]) +
                        __expf(l[i][2]) + __expf(l[i][3]);
        }
        // reduce over the 32 threads (tn) sharing each row
#pragma unroll
        for (int i = 0; i < 4; ++i) {
            float v = s[i];
#pragma unroll
            for (int m = 1; m < 32; m <<= 1) v += __shfl_xor(v, m);
            s[i] = v;
        }
        if (tn == 0) {
            float* dst = sg == 0 ? coefC : (sg == 1 ? coefQK : coefV);
#pragma unroll
            for (int i = 0; i < 4; ++i) {
                int row = row0 + tr * 4 + i;
                dst[row] = imp[row] / s[i];
            }
        }
    }
}

// ---------------------------------------------------------------------------
// K3: recompute logits, accumulate coef*exp(l) into per-block partial dacc
__global__ __launch_bounds__(256) void k_accum(const float* __restrict__ h,
                                               const float* __restrict__ embn,
                                               const float* __restrict__ coefC,
                                               const float* __restrict__ coefQK,
                                               const float* __restrict__ coefV,
                                               float* __restrict__ partials) {
    __shared__ float hs[64][32];
    __shared__ float es[64][128];
    __shared__ float dpart[4096];
    __shared__ float dp2[8][128];
    int t    = threadIdx.x;
    int row0 = blockIdx.x * 32;
    {
        int r = t >> 3, k0 = (t & 7) * 8;
        const float* hp = h + (size_t)(row0 + r) * 64 + k0;
        float4 a = *(const float4*)hp;
        float4 c = *(const float4*)(hp + 4);
        float av[8] = {a.x, a.y, a.z, a.w, c.x, c.y, c.z, c.w};
#pragma unroll
        for (int q = 0; q < 8; ++q) hs[k0 + q][r] = av[q];
    }
    int tr = t >> 5, tn = t & 31;
    const int segB[4] = {0, 2048, 3072, 4096};
    for (int sg = 0; sg < 3; ++sg) {
        const float* cf = sg == 0 ? coefC : (sg == 1 ? coefQK : coefV);
        float coef[4];
#pragma unroll
        for (int i = 0; i < 4; ++i) coef[i] = cf[row0 + tr * 4 + i];
        for (int nb = segB[sg]; nb < segB[sg + 1]; nb += 128) {
            __syncthreads();
            {
                int n = t >> 1, k0 = (t & 1) * 32;
                const float* ep = embn + (size_t)(nb + n) * 64 + k0;
#pragma unroll
                for (int q = 0; q < 8; ++q) {
                    float4 e = *(const float4*)(ep + q * 4);
                    int k = k0 + q * 4;
                    es[k + 0][n] = e.x; es[k + 1][n] = e.y;
                    es[k + 2][n] = e.z; es[k + 3][n] = e.w;
                }
            }
            __syncthreads();
            float l[4][4] = {};
#pragma unroll 8
            for (int k = 0; k < 64; ++k) {
                float4 a4 = *(const float4*)&hs[k][tr * 4];
                float4 e4 = *(const float4*)&es[k][tn * 4];
                float aa[4] = {a4.x, a4.y, a4.z, a4.w};
                float ee[4] = {e4.x, e4.y, e4.z, e4.w};
#pragma unroll
                for (int i = 0; i < 4; ++i)
#pragma unroll
                    for (int j = 0; j < 4; ++j) l[i][j] += aa[i] * ee[j];
            }
            float part[4];
#pragma unroll
            for (int j = 0; j < 4; ++j)
                part[j] = coef[0] * __expf(l[0][j]) + coef[1] * __expf(l[1][j]) +
                          coef[2] * __expf(l[2][j]) + coef[3] * __expf(l[3][j]);
            *(float4*)&dp2[tr][tn * 4] =
                make_float4(part[0], part[1], part[2], part[3]);
            __syncthreads();
            if (t < 128) {
                float sm = 0.f;
#pragma unroll
                for (int g = 0; g < 8; ++g) sm += dp2[g][t];
                dpart[nb + t] = sm;
            }
        }
    }
    __syncthreads();
    int b    = row0 >> 12;            // 4096 rows per batch
    int slot = blockIdx.x & 127;      // 128 blocks per batch
    float* dst = partials + ((size_t)(b * 128 + slot)) * 4096;
#pragma unroll
    for (int q = 0; q < 4; ++q) {
        int n = (q * 256 + t) * 4;
        *(float4*)&dst[n] = *(const float4*)&dpart[n];
    }
}

// ---------------------------------------------------------------------------
// K4a: reduce 128 partial slots per batch -> dacc[4][4096]
__global__ __launch_bounds__(256) void k_reduce(const float* __restrict__ partials,
                                                float* __restrict__ dacc) {
    int blk = blockIdx.x;       // 64 blocks: 16 per batch
    int b   = blk >> 4;
    int n   = (blk & 15) * 256 + threadIdx.x;
    const float* p = partials + (size_t)b * 128 * 4096 + n;
    float s0 = 0.f, s1 = 0.f, s2 = 0.f, s3 = 0.f;
#pragma unroll 4
    for (int s = 0; s < 128; s += 4) {
        s0 += p[(size_t)(s + 0) * 4096];
        s1 += p[(size_t)(s + 1) * 4096];
        s2 += p[(size_t)(s + 2) * 4096];
        s3 += p[(size_t)(s + 3) * 4096];
    }
    dacc[b * 4096 + n] = (s0 + s1) + (s2 + s3);
}

// ---------------------------------------------------------------------------
// K4b: per-batch top-k sparsify + normalize + write all 5120 outputs
__global__ __launch_bounds__(256) void k_topk(const float* __restrict__ dacc,
                                              float* __restrict__ out) {
    __shared__ float dv[4096];
    __shared__ float redv[4];
    __shared__ int   redi[4];
    __shared__ float selv[8];
    __shared__ int   seli[8];
    int b = blockIdx.x, t = threadIdx.x;
#pragma unroll
    for (int q = 0; q < 16; ++q) dv[q * 256 + t] = dacc[b * 4096 + q * 256 + t];
    __syncthreads();
    const int segStart[3] = {0, 2048, 3072};
    const int segLen[3]   = {2048, 1024, 1024};
    const int segK[3]     = {8, 4, 6};
    const int segOut[3]   = {0, 2048, 4096};
    for (int sg = 0; sg < 3; ++sg) {
        int st = segStart[sg], len = segLen[sg], kk = segK[sg];
        for (int it = 0; it < kk; ++it) {
            float bv = -3.0e38f;
            int   bi = 1 << 30;
            for (int n = t; n < len; n += 256) {
                float v = dv[st + n];
                if (v > bv) { bv = v; bi = n; }  // strict > keeps lowest idx
            }
#pragma unroll
            for (int m = 1; m < 64; m <<= 1) {
                float ov = __shfl_xor(bv, m);
                int   oi = __shfl_xor(bi, m);
                if (ov > bv || (ov == bv && oi < bi)) { bv = ov; bi = oi; }
            }
            if ((t & 63) == 0) { redv[t >> 6] = bv; redi[t >> 6] = bi; }
            __syncthreads();
            if (t == 0) {
                for (int w = 1; w < 4; ++w)
                    if (redv[w] > bv || (redv[w] == bv && redi[w] < bi)) {
                        bv = redv[w]; bi = redi[w];
                    }
                selv[it] = bv;
                seli[it] = bi;
                dv[st + bi] = -3.4e38f;
            }
            __syncthreads();
        }
        float sum = 0.f;
        for (int it = 0; it < kk; ++it) sum += selv[it];
        float inv = 1.0f / (sum + 1e-8f);
        for (int n = t; n < len; n += 256) {
            float v = 0.0f;
            for (int it = 0; it < kk; ++it)
                if (seli[it] == n) v = selv[it] * inv;
            out[b * 5120 + segOut[sg] + n] = v;
            if (sg == 1) out[b * 5120 + 3072 + n] = v;  // wK == wQ
        }
        __syncthreads();
    }
}

// ---------------------------------------------------------------------------
extern "C" void kernel_launch(void* const* d_in, const int* in_sizes, int n_in,
                              void* d_out, int out_size, void* d_ws, size_t ws_size,
                              hipStream_t stream) {
    (void)in_sizes; (void)n_in; (void)out_size; (void)ws_size;
    const float* x    = (const float*)d_in[0];
    const float* imp  = (const float*)d_in[1];
    const float* W    = (const float*)d_in[2];
    const float* bias = (const float*)d_in[3];
    const float* emb  = (const float*)d_in[4];
    float* out = (float*)d_out;
    float* ws  = (float*)d_ws;

    // workspace layout (floats): ~13.9 MB total
    float* embn     = ws;                    // 4096*64      = 262144
    float* h        = ws + 262144;           // 16384*64     = 1048576
    float* coefC    = ws + 1310720;          // 16384
    float* coefQK   = ws + 1327104;          // 16384
    float* coefV    = ws + 1343488;          // 16384
    float* partials = ws + 1359872;          // 4*128*4096   = 2097152
    float* dacc     = ws + 3457024;          // 16384

    hipLaunchKernelGGL(k_norm,   dim3(1024), dim3(256), 0, stream, emb, embn);
    hipLaunchKernelGGL(k_hgemm,  dim3(256),  dim3(256), 0, stream, x, W, bias, h);
    hipLaunchKernelGGL(k_zpass,  dim3(512),  dim3(256), 0, stream, h, embn, imp,
                       coefC, coefQK, coefV);
    hipLaunchKernelGGL(k_accum,  dim3(512),  dim3(256), 0, stream, h, embn,
                       coefC, coefQK, coefV, partials);
    hipLaunchKernelGGL(k_reduce, dim3(64),   dim3(256), 0, stream, partials, dacc);
    hipLaunchKernelGGL(k_topk,   dim3(4),    dim3(256), 0, stream, dacc, out);
}

// Round 2
// 465.409 us; speedup vs baseline: 1.3172x; 1.3172x over previous
//
#include <hip/hip_runtime.h>
#include <math.h>

// x: [4][4096][2048] f32, importance: [4][4096] f32, W: [2048][64] f32,
// b: [64] f32, neuron_emb: [4096][64] f32
// out: [4][5120] f32  (wC 2048 | wQ 1024 | wK 1024 (==wQ) | wV 1024)
#define D_IN   2048

typedef __bf16 bf16x8 __attribute__((ext_vector_type(8)));
typedef __bf16 bf16x4 __attribute__((ext_vector_type(4)));
typedef float  f32x16 __attribute__((ext_vector_type(16)));

// ---------------------------------------------------------------------------
// K0: normalize neuron embeddings and split into hi/lo bf16
__global__ __launch_bounds__(256) void k_prepe(const float* __restrict__ emb,
                                               __bf16* __restrict__ e_hi,
                                               __bf16* __restrict__ e_lo) {
    int gid  = blockIdx.x * 256 + threadIdx.x;
    int row  = gid >> 6;
    int lane = gid & 63;
    float v  = emb[row * 64 + lane];
    float ss = v * v;
#pragma unroll
    for (int m = 32; m >= 1; m >>= 1) ss += __shfl_xor(ss, m);
    float nv = v / sqrtf(ss);
    __bf16 hb = (__bf16)nv;
    e_hi[row * 64 + lane] = hb;
    e_lo[row * 64 + lane] = (__bf16)(nv - (float)hb);
}

// ---------------------------------------------------------------------------
// K1: h = x @ W + b   (16384x2048 @ 2048x64), fp32 vector GEMM
// epilogue writes h split into hi/lo bf16
__global__ __launch_bounds__(256) void k_hgemm(const float* __restrict__ x,
                                               const float* __restrict__ W,
                                               const float* __restrict__ bias,
                                               __bf16* __restrict__ h_hi,
                                               __bf16* __restrict__ h_lo) {
    __shared__ float xs[32][64];  // [k][row]
    __shared__ float ws[32][64];  // [k][col]
    int t    = threadIdx.x;
    int row0 = blockIdx.x * 64;
    int lr   = t >> 2;            // 0..63 staging row
    int kq   = (t & 3) * 8;       // staging k offset
    int kw   = t >> 3;            // 0..31 W staging k
    int cq   = (t & 7) * 8;       // W staging col offset
    int tr   = t >> 4;            // 0..15 -> rows tr*4..+3
    int tc   = t & 15;            // cols tc*4..+3
    float acc[4][4] = {};
    for (int k0 = 0; k0 < D_IN; k0 += 32) {
        const float* xp = x + (size_t)(row0 + lr) * D_IN + k0 + kq;
        float4 a  = *(const float4*)xp;
        float4 c  = *(const float4*)(xp + 4);
        const float* wp = W + (size_t)(k0 + kw) * 64 + cq;
        float4 w0 = *(const float4*)wp;
        float4 w1 = *(const float4*)(wp + 4);
        __syncthreads();
        {
            float av[8] = {a.x, a.y, a.z, a.w, c.x, c.y, c.z, c.w};
#pragma unroll
            for (int q = 0; q < 8; ++q) xs[kq + q][lr] = av[q];
        }
        *(float4*)&ws[kw][cq]     = w0;
        *(float4*)&ws[kw][cq + 4] = w1;
        __syncthreads();
#pragma unroll 8
        for (int k = 0; k < 32; ++k) {
            float4 av4 = *(const float4*)&xs[k][tr * 4];
            float4 bv4 = *(const float4*)&ws[k][tc * 4];
            float aa[4] = {av4.x, av4.y, av4.z, av4.w};
            float bb[4] = {bv4.x, bv4.y, bv4.z, bv4.w};
#pragma unroll
            for (int i = 0; i < 4; ++i)
#pragma unroll
                for (int j = 0; j < 4; ++j) acc[i][j] += aa[i] * bb[j];
        }
    }
    float4 bb4 = *(const float4*)&bias[tc * 4];
    float bs[4] = {bb4.x, bb4.y, bb4.z, bb4.w};
#pragma unroll
    for (int i = 0; i < 4; ++i) {
        int row = row0 + tr * 4 + i;
        bf16x4 vhi, vlo;
#pragma unroll
        for (int j = 0; j < 4; ++j) {
            float v  = acc[i][j] + bs[j];
            __bf16 hb = (__bf16)v;
            vhi[j] = hb;
            vlo[j] = (__bf16)(v - (float)hb);
        }
        *(bf16x4*)&h_hi[(size_t)row * 64 + tc * 4] = vhi;
        *(bf16x4*)&h_lo[(size_t)row * 64 + tc * 4] = vlo;
    }
}

// ---------------------------------------------------------------------------
// K2: fused Z-pass + weighted-accumulate via split-bf16 MFMA.
// Block = 64 rows (2 row-groups x 32), 8 waves (2 row x 4 col groups).
// Each wave: 32 rows x 32 neurons per 128-neuron chunk, K=64, 12 MFMAs
// (hi*hi + hi*lo + lo*hi) per chunk.  Per segment: sweep Z, reduce
// (shfl within 32 lanes + LDS across col-waves), coef = imp/Z, sweep again
// accumulating coef*exp(l) -> partials[batch][slot][4096].
__global__ __launch_bounds__(512, 2) void k_logits(
        const __bf16* __restrict__ h_hi, const __bf16* __restrict__ h_lo,
        const __bf16* __restrict__ e_hi, const __bf16* __restrict__ e_lo,
        const float* __restrict__ imp, float* __restrict__ partials) {
    __shared__ float zs[8][2][16];
    int t    = threadIdx.x;
    int wave = t >> 6;
    int lane = t & 63;
    int l31  = lane & 31;
    int h5   = lane >> 5;
    int wr   = wave >> 2;   // row-group 0..1
    int wc   = wave & 3;    // col-group 0..3
    int row0 = blockIdx.x * 64 + wr * 32;

    // A fragments (persistent): A[m=l31][k = ks*16 + h5*8 + j]
    bf16x8 a_hi[4], a_lo[4];
    {
        const __bf16* hp = h_hi + (size_t)(row0 + l31) * 64 + h5 * 8;
        const __bf16* lp = h_lo + (size_t)(row0 + l31) * 64 + h5 * 8;
#pragma unroll
        for (int ks = 0; ks < 4; ++ks) {
            a_hi[ks] = *(const bf16x8*)(hp + ks * 16);
            a_lo[ks] = *(const bf16x8*)(lp + ks * 16);
        }
    }
    float impv[16];
#pragma unroll
    for (int r = 0; r < 16; ++r)
        impv[r] = imp[row0 + (r & 3) + 8 * (r >> 2) + 4 * h5];

    int b    = blockIdx.x >> 6;          // 64 blocks per batch
    int slot = (blockIdx.x & 63) * 2 + wr;
    float* pbase = partials + ((size_t)(b * 128 + slot)) * 4096;

    const int segB[4] = {0, 2048, 3072, 4096};
    for (int sg = 0; sg < 3; ++sg) {
        // ---- pass A: Z ----
        float zacc[16];
#pragma unroll
        for (int r = 0; r < 16; ++r) zacc[r] = 0.f;
        for (int nb = segB[sg]; nb < segB[sg + 1]; nb += 128) {
            const __bf16* ep = e_hi + (size_t)(nb + wc * 32 + l31) * 64 + h5 * 8;
            const __bf16* lp = e_lo + (size_t)(nb + wc * 32 + l31) * 64 + h5 * 8;
            bf16x8 b_hi[4], b_lo[4];
#pragma unroll
            for (int ks = 0; ks < 4; ++ks) {
                b_hi[ks] = *(const bf16x8*)(ep + ks * 16);
                b_lo[ks] = *(const bf16x8*)(lp + ks * 16);
            }
            f32x16 acc = {0.f,0.f,0.f,0.f,0.f,0.f,0.f,0.f,
                          0.f,0.f,0.f,0.f,0.f,0.f,0.f,0.f};
#pragma unroll
            for (int ks = 0; ks < 4; ++ks) {
                acc = __builtin_amdgcn_mfma_f32_32x32x16_bf16(a_hi[ks], b_hi[ks], acc, 0, 0, 0);
                acc = __builtin_amdgcn_mfma_f32_32x32x16_bf16(a_hi[ks], b_lo[ks], acc, 0, 0, 0);
                acc = __builtin_amdgcn_mfma_f32_32x32x16_bf16(a_lo[ks], b_hi[ks], acc, 0, 0, 0);
            }
#pragma unroll
            for (int r = 0; r < 16; ++r) zacc[r] += __expf(acc[r]);
        }
        // reduce across 32 lanes (neurons within wave), then across col-waves
#pragma unroll
        for (int r = 0; r < 16; ++r) {
            float z = zacc[r];
#pragma unroll
            for (int m = 1; m < 32; m <<= 1) z += __shfl_xor(z, m);
            zacc[r] = z;
        }
        if (l31 == 0) {
#pragma unroll
            for (int r = 0; r < 16; ++r) zs[wave][h5][r] = zacc[r];
        }
        __syncthreads();
        float coef[16];
#pragma unroll
        for (int r = 0; r < 16; ++r) {
            float z = zs[wr * 4 + 0][h5][r] + zs[wr * 4 + 1][h5][r] +
                      zs[wr * 4 + 2][h5][r] + zs[wr * 4 + 3][h5][r];
            coef[r] = impv[r] / z;
        }
        __syncthreads();  // zs reused next segment
        // ---- pass B: accumulate coef * exp(l) ----
        for (int nb = segB[sg]; nb < segB[sg + 1]; nb += 128) {
            const __bf16* ep = e_hi + (size_t)(nb + wc * 32 + l31) * 64 + h5 * 8;
            const __bf16* lp = e_lo + (size_t)(nb + wc * 32 + l31) * 64 + h5 * 8;
            bf16x8 b_hi[4], b_lo[4];
#pragma unroll
            for (int ks = 0; ks < 4; ++ks) {
                b_hi[ks] = *(const bf16x8*)(ep + ks * 16);
                b_lo[ks] = *(const bf16x8*)(lp + ks * 16);
            }
            f32x16 acc = {0.f,0.f,0.f,0.f,0.f,0.f,0.f,0.f,
                          0.f,0.f,0.f,0.f,0.f,0.f,0.f,0.f};
#pragma unroll
            for (int ks = 0; ks < 4; ++ks) {
                acc = __builtin_amdgcn_mfma_f32_32x32x16_bf16(a_hi[ks], b_hi[ks], acc, 0, 0, 0);
                acc = __builtin_amdgcn_mfma_f32_32x32x16_bf16(a_hi[ks], b_lo[ks], acc, 0, 0, 0);
                acc = __builtin_amdgcn_mfma_f32_32x32x16_bf16(a_lo[ks], b_hi[ks], acc, 0, 0, 0);
            }
            float s = 0.f;
#pragma unroll
            for (int r = 0; r < 16; ++r) s += coef[r] * __expf(acc[r]);
            s += __shfl_xor(s, 32);  // combine the two 16-row halves
            if (h5 == 0) pbase[nb + wc * 32 + l31] = s;
        }
    }
}

// ---------------------------------------------------------------------------
// K4a: reduce 128 partial slots per batch -> dacc[4][4096]
__global__ __launch_bounds__(256) void k_reduce(const float* __restrict__ partials,
                                                float* __restrict__ dacc) {
    int blk = blockIdx.x;       // 64 blocks: 16 per batch
    int b   = blk >> 4;
    int n   = (blk & 15) * 256 + threadIdx.x;
    const float* p = partials + (size_t)b * 128 * 4096 + n;
    float s0 = 0.f, s1 = 0.f, s2 = 0.f, s3 = 0.f;
#pragma unroll 4
    for (int s = 0; s < 128; s += 4) {
        s0 += p[(size_t)(s + 0) * 4096];
        s1 += p[(size_t)(s + 1) * 4096];
        s2 += p[(size_t)(s + 2) * 4096];
        s3 += p[(size_t)(s + 3) * 4096];
    }
    dacc[b * 4096 + n] = (s0 + s1) + (s2 + s3);
}

// ---------------------------------------------------------------------------
// K4b: per-batch top-k sparsify + normalize + write all 5120 outputs
__global__ __launch_bounds__(256) void k_topk(const float* __restrict__ dacc,
                                              float* __restrict__ out) {
    __shared__ float dv[4096];
    __shared__ float redv[4];
    __shared__ int   redi[4];
    __shared__ float selv[8];
    __shared__ int   seli[8];
    int b = blockIdx.x, t = threadIdx.x;
#pragma unroll
    for (int q = 0; q < 16; ++q) dv[q * 256 + t] = dacc[b * 4096 + q * 256 + t];
    __syncthreads();
    const int segStart[3] = {0, 2048, 3072};
    const int segLen[3]   = {2048, 1024, 1024};
    const int segK[3]     = {8, 4, 6};
    const int segOut[3]   = {0, 2048, 4096};
    for (int sg = 0; sg < 3; ++sg) {
        int st = segStart[sg], len = segLen[sg], kk = segK[sg];
        for (int it = 0; it < kk; ++it) {
            float bv = -3.0e38f;
            int   bi = 1 << 30;
            for (int n = t; n < len; n += 256) {
                float v = dv[st + n];
                if (v > bv) { bv = v; bi = n; }
            }
#pragma unroll
            for (int m = 1; m < 64; m <<= 1) {
                float ov = __shfl_xor(bv, m);
                int   oi = __shfl_xor(bi, m);
                if (ov > bv || (ov == bv && oi < bi)) { bv = ov; bi = oi; }
            }
            if ((t & 63) == 0) { redv[t >> 6] = bv; redi[t >> 6] = bi; }
            __syncthreads();
            if (t == 0) {
                for (int w = 1; w < 4; ++w)
                    if (redv[w] > bv || (redv[w] == bv && redi[w] < bi)) {
                        bv = redv[w]; bi = redi[w];
                    }
                selv[it] = bv;
                seli[it] = bi;
                dv[st + bi] = -3.4e38f;
            }
            __syncthreads();
        }
        float sum = 0.f;
        for (int it = 0; it < kk; ++it) sum += selv[it];
        float inv = 1.0f / (sum + 1e-8f);
        for (int n = t; n < len; n += 256) {
            float v = 0.0f;
            for (int it = 0; it < kk; ++it)
                if (seli[it] == n) v = selv[it] * inv;
            out[b * 5120 + segOut[sg] + n] = v;
            if (sg == 1) out[b * 5120 + 3072 + n] = v;  // wK == wQ
        }
        __syncthreads();
    }
}

// ---------------------------------------------------------------------------
extern "C" void kernel_launch(void* const* d_in, const int* in_sizes, int n_in,
                              void* d_out, int out_size, void* d_ws, size_t ws_size,
                              hipStream_t stream) {
    (void)in_sizes; (void)n_in; (void)out_size; (void)ws_size;
    const float* x    = (const float*)d_in[0];
    const float* imp  = (const float*)d_in[1];
    const float* W    = (const float*)d_in[2];
    const float* bias = (const float*)d_in[3];
    const float* emb  = (const float*)d_in[4];
    float* out = (float*)d_out;

    // workspace layout (bytes): ~13.1 MB total
    char* w = (char*)d_ws;
    __bf16* e_hi = (__bf16*)w;            w += (size_t)4096 * 64 * 2;    // 512KB
    __bf16* e_lo = (__bf16*)w;            w += (size_t)4096 * 64 * 2;    // 512KB
    __bf16* h_hi = (__bf16*)w;            w += (size_t)16384 * 64 * 2;   // 2MB
    __bf16* h_lo = (__bf16*)w;            w += (size_t)16384 * 64 * 2;   // 2MB
    float* partials = (float*)w;          w += (size_t)4 * 128 * 4096 * 4; // 8MB
    float* dacc = (float*)w;              w += (size_t)4 * 4096 * 4;     // 64KB

    hipLaunchKernelGGL(k_prepe,  dim3(1024), dim3(256), 0, stream, emb, e_hi, e_lo);
    hipLaunchKernelGGL(k_hgemm,  dim3(256),  dim3(256), 0, stream, x, W, bias, h_hi, h_lo);
    hipLaunchKernelGGL(k_logits, dim3(256),  dim3(512), 0, stream, h_hi, h_lo,
                       e_hi, e_lo, imp, partials);
    hipLaunchKernelGGL(k_reduce, dim3(64),   dim3(256), 0, stream, partials, dacc);
    hipLaunchKernelGGL(k_topk,   dim3(4),    dim3(256), 0, stream, dacc, out);
}

// Round 3
// 402.754 us; speedup vs baseline: 1.5221x; 1.1556x over previous
//
#include <hip/hip_runtime.h>
#include <math.h>

// x: [4][4096][2048] f32, importance: [4][4096] f32, W: [2048][64] f32,
// b: [64] f32, neuron_emb: [4096][64] f32
// out: [4][5120] f32  (wC 2048 | wQ 1024 | wK 1024 (==wQ) | wV 1024)
#define D_IN   2048

typedef __bf16 bf16x8 __attribute__((ext_vector_type(8)));
typedef __bf16 bf16x4 __attribute__((ext_vector_type(4)));
typedef float  f32x4  __attribute__((ext_vector_type(4)));
typedef float  f32x16 __attribute__((ext_vector_type(16)));

// ---------------------------------------------------------------------------
// K0a: normalize neuron embeddings and split into hi/lo bf16
__global__ __launch_bounds__(256) void k_prepe(const float* __restrict__ emb,
                                               __bf16* __restrict__ e_hi,
                                               __bf16* __restrict__ e_lo) {
    int gid  = blockIdx.x * 256 + threadIdx.x;
    int row  = gid >> 6;
    int lane = gid & 63;
    float v  = emb[row * 64 + lane];
    float ss = v * v;
#pragma unroll
    for (int m = 32; m >= 1; m >>= 1) ss += __shfl_xor(ss, m);
    float nv = v / sqrtf(ss);
    __bf16 hb = (__bf16)nv;
    e_hi[row * 64 + lane] = hb;
    e_lo[row * 64 + lane] = (__bf16)(nv - (float)hb);
}

// ---------------------------------------------------------------------------
// K0b: transpose + split W -> Wt_hi/Wt_lo [64][2048] bf16
__global__ __launch_bounds__(256) void k_prepw(const float* __restrict__ W,
                                               __bf16* __restrict__ wt_hi,
                                               __bf16* __restrict__ wt_lo) {
    int gid = blockIdx.x * 256 + threadIdx.x;   // 131072 total
    int c   = gid >> 11;
    int k   = gid & 2047;
    float v = W[k * 64 + c];
    __bf16 hb = (__bf16)v;
    wt_hi[c * 2048 + k] = hb;
    wt_lo[c * 2048 + k] = (__bf16)(v - (float)hb);
}

// ---------------------------------------------------------------------------
// K1: h-partial = x[:, kh*1024:+1024] @ W-half via split-bf16 MFMA 16x16x32.
// 512 blocks (256 row-blocks x 2 K-halves), 4 waves/block, 16 rows/wave.
// No LDS; A streamed global->reg with even/odd prefetch; B (Wt) L2-resident.
__global__ __launch_bounds__(256, 2) void k_hgemm_mfma(
        const float* __restrict__ x,
        const __bf16* __restrict__ wt_hi, const __bf16* __restrict__ wt_lo,
        float* __restrict__ pc) {
    int t     = threadIdx.x;
    int wave  = t >> 6;
    int lane  = t & 63;
    int l15   = lane & 15;
    int kg    = lane >> 4;          // 0..3  (k subgroup)
    int rblk  = blockIdx.x & 255;
    int kh    = blockIdx.x >> 8;    // 0..1
    int row0  = rblk * 64 + wave * 16;
    int kbase = kh * 1024;

    const float*  xp    = x + (size_t)(row0 + l15) * D_IN + kbase + kg * 8;
    const __bf16* bh_p0 = wt_hi + (size_t)(0  + l15) * D_IN + kbase + kg * 8;
    const __bf16* bh_p1 = bh_p0 + 16 * D_IN;
    const __bf16* bh_p2 = bh_p0 + 32 * D_IN;
    const __bf16* bh_p3 = bh_p0 + 48 * D_IN;
    const __bf16* bl_p0 = wt_lo + (size_t)(0  + l15) * D_IN + kbase + kg * 8;
    const __bf16* bl_p1 = bl_p0 + 16 * D_IN;
    const __bf16* bl_p2 = bl_p0 + 32 * D_IN;
    const __bf16* bl_p3 = bl_p0 + 48 * D_IN;

    f32x4 acc0 = {0.f,0.f,0.f,0.f}, acc1 = {0.f,0.f,0.f,0.f};
    f32x4 acc2 = {0.f,0.f,0.f,0.f}, acc3 = {0.f,0.f,0.f,0.f};

    float4 e_a0, e_a1, o_a0, o_a1;
    bf16x8 e_bh0, e_bh1, e_bh2, e_bh3, e_bl0, e_bl1, e_bl2, e_bl3;
    bf16x8 o_bh0, o_bh1, o_bh2, o_bh3, o_bl0, o_bl1, o_bl2, o_bl3;

#define LDA(S, KO) { S##_a0 = *(const float4*)(xp + (KO)); \
                     S##_a1 = *(const float4*)(xp + (KO) + 4); }
#define LDB(S, KO) { S##_bh0 = *(const bf16x8*)(bh_p0 + (KO)); \
                     S##_bh1 = *(const bf16x8*)(bh_p1 + (KO)); \
                     S##_bh2 = *(const bf16x8*)(bh_p2 + (KO)); \
                     S##_bh3 = *(const bf16x8*)(bh_p3 + (KO)); \
                     S##_bl0 = *(const bf16x8*)(bl_p0 + (KO)); \
                     S##_bl1 = *(const bf16x8*)(bl_p1 + (KO)); \
                     S##_bl2 = *(const bf16x8*)(bl_p2 + (KO)); \
                     S##_bl3 = *(const bf16x8*)(bl_p3 + (KO)); }
#define COMP(S) { \
    float av[8] = {S##_a0.x, S##_a0.y, S##_a0.z, S##_a0.w, \
                   S##_a1.x, S##_a1.y, S##_a1.z, S##_a1.w}; \
    bf16x8 ah, al; \
    _Pragma("unroll") \
    for (int j = 0; j < 8; ++j) { \
        __bf16 hb = (__bf16)av[j]; ah[j] = hb; \
        al[j] = (__bf16)(av[j] - (float)hb); \
    } \
    acc0 = __builtin_amdgcn_mfma_f32_16x16x32_bf16(ah, S##_bh0, acc0, 0, 0, 0); \
    acc1 = __builtin_amdgcn_mfma_f32_16x16x32_bf16(ah, S##_bh1, acc1, 0, 0, 0); \
    acc2 = __builtin_amdgcn_mfma_f32_16x16x32_bf16(ah, S##_bh2, acc2, 0, 0, 0); \
    acc3 = __builtin_amdgcn_mfma_f32_16x16x32_bf16(ah, S##_bh3, acc3, 0, 0, 0); \
    acc0 = __builtin_amdgcn_mfma_f32_16x16x32_bf16(ah, S##_bl0, acc0, 0, 0, 0); \
    acc1 = __builtin_amdgcn_mfma_f32_16x16x32_bf16(ah, S##_bl1, acc1, 0, 0, 0); \
    acc2 = __builtin_amdgcn_mfma_f32_16x16x32_bf16(ah, S##_bl2, acc2, 0, 0, 0); \
    acc3 = __builtin_amdgcn_mfma_f32_16x16x32_bf16(ah, S##_bl3, acc3, 0, 0, 0); \
    acc0 = __builtin_amdgcn_mfma_f32_16x16x32_bf16(al, S##_bh0, acc0, 0, 0, 0); \
    acc1 = __builtin_amdgcn_mfma_f32_16x16x32_bf16(al, S##_bh1, acc1, 0, 0, 0); \
    acc2 = __builtin_amdgcn_mfma_f32_16x16x32_bf16(al, S##_bh2, acc2, 0, 0, 0); \
    acc3 = __builtin_amdgcn_mfma_f32_16x16x32_bf16(al, S##_bh3, acc3, 0, 0, 0); }

    // 32 K-steps of 32; even/odd software pipeline, last pair peeled
    LDA(e, 0) LDB(e, 0)
#pragma unroll
    for (int it = 0; it < 30; it += 2) {
        LDA(o, (it + 1) * 32) LDB(o, (it + 1) * 32)
        COMP(e)
        LDA(e, (it + 2) * 32) LDB(e, (it + 2) * 32)
        COMP(o)
    }
    LDA(o, 31 * 32) LDB(o, 31 * 32)
    COMP(e)
    COMP(o)
#undef LDA
#undef LDB
#undef COMP

    // C/D 16x16: col = lane&15, row = (lane>>4)*4 + reg
    float* dst = pc + (size_t)kh * 16384 * 64 + (size_t)(row0 + kg * 4) * 64 + l15;
#pragma unroll
    for (int r = 0; r < 4; ++r) {
        dst[(size_t)r * 64 + 0]  = acc0[r];
        dst[(size_t)r * 64 + 16] = acc1[r];
        dst[(size_t)r * 64 + 32] = acc2[r];
        dst[(size_t)r * 64 + 48] = acc3[r];
    }
}

// ---------------------------------------------------------------------------
// K1b: h = pc0 + pc1 + bias, split into hi/lo bf16
__global__ __launch_bounds__(256) void k_hfix(const float* __restrict__ pc,
                                              const float* __restrict__ bias,
                                              __bf16* __restrict__ h_hi,
                                              __bf16* __restrict__ h_lo) {
    int gid = blockIdx.x * 256 + threadIdx.x;  // 262144 total
    int i4  = gid * 4;
    float4 p0 = *(const float4*)(pc + i4);
    float4 p1 = *(const float4*)(pc + (size_t)16384 * 64 + i4);
    float4 bb = *(const float4*)(bias + (i4 & 63));
    float hv[4] = {p0.x + p1.x + bb.x, p0.y + p1.y + bb.y,
                   p0.z + p1.z + bb.z, p0.w + p1.w + bb.w};
    bf16x4 vhi, vlo;
#pragma unroll
    for (int j = 0; j < 4; ++j) {
        __bf16 hb = (__bf16)hv[j];
        vhi[j] = hb;
        vlo[j] = (__bf16)(hv[j] - (float)hb);
    }
    *(bf16x4*)&h_hi[i4] = vhi;
    *(bf16x4*)&h_lo[i4] = vlo;
}

// ---------------------------------------------------------------------------
// K2: fused Z-pass + weighted-accumulate via split-bf16 MFMA (unchanged).
__global__ __launch_bounds__(512, 2) void k_logits(
        const __bf16* __restrict__ h_hi, const __bf16* __restrict__ h_lo,
        const __bf16* __restrict__ e_hi, const __bf16* __restrict__ e_lo,
        const float* __restrict__ imp, float* __restrict__ partials) {
    __shared__ float zs[8][2][16];
    int t    = threadIdx.x;
    int wave = t >> 6;
    int lane = t & 63;
    int l31  = lane & 31;
    int h5   = lane >> 5;
    int wr   = wave >> 2;   // row-group 0..1
    int wc   = wave & 3;    // col-group 0..3
    int row0 = blockIdx.x * 64 + wr * 32;

    bf16x8 a_hi[4], a_lo[4];
    {
        const __bf16* hp = h_hi + (size_t)(row0 + l31) * 64 + h5 * 8;
        const __bf16* lp = h_lo + (size_t)(row0 + l31) * 64 + h5 * 8;
#pragma unroll
        for (int ks = 0; ks < 4; ++ks) {
            a_hi[ks] = *(const bf16x8*)(hp + ks * 16);
            a_lo[ks] = *(const bf16x8*)(lp + ks * 16);
        }
    }
    float impv[16];
#pragma unroll
    for (int r = 0; r < 16; ++r)
        impv[r] = imp[row0 + (r & 3) + 8 * (r >> 2) + 4 * h5];

    int b    = blockIdx.x >> 6;          // 64 blocks per batch
    int slot = (blockIdx.x & 63) * 2 + wr;
    float* pbase = partials + ((size_t)(b * 128 + slot)) * 4096;

    const int segB[4] = {0, 2048, 3072, 4096};
    for (int sg = 0; sg < 3; ++sg) {
        float zacc[16];
#pragma unroll
        for (int r = 0; r < 16; ++r) zacc[r] = 0.f;
        for (int nb = segB[sg]; nb < segB[sg + 1]; nb += 128) {
            const __bf16* ep = e_hi + (size_t)(nb + wc * 32 + l31) * 64 + h5 * 8;
            const __bf16* lp = e_lo + (size_t)(nb + wc * 32 + l31) * 64 + h5 * 8;
            bf16x8 b_hi[4], b_lo[4];
#pragma unroll
            for (int ks = 0; ks < 4; ++ks) {
                b_hi[ks] = *(const bf16x8*)(ep + ks * 16);
                b_lo[ks] = *(const bf16x8*)(lp + ks * 16);
            }
            f32x16 acc = {0.f,0.f,0.f,0.f,0.f,0.f,0.f,0.f,
                          0.f,0.f,0.f,0.f,0.f,0.f,0.f,0.f};
#pragma unroll
            for (int ks = 0; ks < 4; ++ks) {
                acc = __builtin_amdgcn_mfma_f32_32x32x16_bf16(a_hi[ks], b_hi[ks], acc, 0, 0, 0);
                acc = __builtin_amdgcn_mfma_f32_32x32x16_bf16(a_hi[ks], b_lo[ks], acc, 0, 0, 0);
                acc = __builtin_amdgcn_mfma_f32_32x32x16_bf16(a_lo[ks], b_hi[ks], acc, 0, 0, 0);
            }
#pragma unroll
            for (int r = 0; r < 16; ++r) zacc[r] += __expf(acc[r]);
        }
#pragma unroll
        for (int r = 0; r < 16; ++r) {
            float z = zacc[r];
#pragma unroll
            for (int m = 1; m < 32; m <<= 1) z += __shfl_xor(z, m);
            zacc[r] = z;
        }
        if (l31 == 0) {
#pragma unroll
            for (int r = 0; r < 16; ++r) zs[wave][h5][r] = zacc[r];
        }
        __syncthreads();
        float coef[16];
#pragma unroll
        for (int r = 0; r < 16; ++r) {
            float z = zs[wr * 4 + 0][h5][r] + zs[wr * 4 + 1][h5][r] +
                      zs[wr * 4 + 2][h5][r] + zs[wr * 4 + 3][h5][r];
            coef[r] = impv[r] / z;
        }
        __syncthreads();  // zs reused next segment
        for (int nb = segB[sg]; nb < segB[sg + 1]; nb += 128) {
            const __bf16* ep = e_hi + (size_t)(nb + wc * 32 + l31) * 64 + h5 * 8;
            const __bf16* lp = e_lo + (size_t)(nb + wc * 32 + l31) * 64 + h5 * 8;
            bf16x8 b_hi[4], b_lo[4];
#pragma unroll
            for (int ks = 0; ks < 4; ++ks) {
                b_hi[ks] = *(const bf16x8*)(ep + ks * 16);
                b_lo[ks] = *(const bf16x8*)(lp + ks * 16);
            }
            f32x16 acc = {0.f,0.f,0.f,0.f,0.f,0.f,0.f,0.f,
                          0.f,0.f,0.f,0.f,0.f,0.f,0.f,0.f};
#pragma unroll
            for (int ks = 0; ks < 4; ++ks) {
                acc = __builtin_amdgcn_mfma_f32_32x32x16_bf16(a_hi[ks], b_hi[ks], acc, 0, 0, 0);
                acc = __builtin_amdgcn_mfma_f32_32x32x16_bf16(a_hi[ks], b_lo[ks], acc, 0, 0, 0);
                acc = __builtin_amdgcn_mfma_f32_32x32x16_bf16(a_lo[ks], b_hi[ks], acc, 0, 0, 0);
            }
            float s = 0.f;
#pragma unroll
            for (int r = 0; r < 16; ++r) s += coef[r] * __expf(acc[r]);
            s += __shfl_xor(s, 32);
            if (h5 == 0) pbase[nb + wc * 32 + l31] = s;
        }
    }
}

// ---------------------------------------------------------------------------
// K4a: reduce 128 partial slots per batch -> dacc[4][4096]
__global__ __launch_bounds__(256) void k_reduce(const float* __restrict__ partials,
                                                float* __restrict__ dacc) {
    int blk = blockIdx.x;       // 64 blocks: 16 per batch
    int b   = blk >> 4;
    int n   = (blk & 15) * 256 + threadIdx.x;
    const float* p = partials + (size_t)b * 128 * 4096 + n;
    float s0 = 0.f, s1 = 0.f, s2 = 0.f, s3 = 0.f;
#pragma unroll 4
    for (int s = 0; s < 128; s += 4) {
        s0 += p[(size_t)(s + 0) * 4096];
        s1 += p[(size_t)(s + 1) * 4096];
        s2 += p[(size_t)(s + 2) * 4096];
        s3 += p[(size_t)(s + 3) * 4096];
    }
    dacc[b * 4096 + n] = (s0 + s1) + (s2 + s3);
}

// ---------------------------------------------------------------------------
// K4b: top-k sparsify; one block per (batch, segment) -> 12 blocks
__global__ __launch_bounds__(256) void k_topk(const float* __restrict__ dacc,
                                              float* __restrict__ out) {
    __shared__ float dv[2048];
    __shared__ float redv[4];
    __shared__ int   redi[4];
    __shared__ float selv[8];
    __shared__ int   seli[8];
    int blk = blockIdx.x;
    int b   = blk / 3;
    int sg  = blk - 3 * b;
    int t   = threadIdx.x;
    const int segStart[3] = {0, 2048, 3072};
    const int segLen[3]   = {2048, 1024, 1024};
    const int segK[3]     = {8, 4, 6};
    const int segOut[3]   = {0, 2048, 4096};
    int st = segStart[sg], len = segLen[sg], kk = segK[sg];
    for (int n = t; n < len; n += 256) dv[n] = dacc[b * 4096 + st + n];
    __syncthreads();
    for (int it = 0; it < kk; ++it) {
        float bv = -3.0e38f;
        int   bi = 1 << 30;
        for (int n = t; n < len; n += 256) {
            float v = dv[n];
            if (v > bv) { bv = v; bi = n; }  // strict > keeps lowest idx
        }
#pragma unroll
        for (int m = 1; m < 64; m <<= 1) {
            float ov = __shfl_xor(bv, m);
            int   oi = __shfl_xor(bi, m);
            if (ov > bv || (ov == bv && oi < bi)) { bv = ov; bi = oi; }
        }
        if ((t & 63) == 0) { redv[t >> 6] = bv; redi[t >> 6] = bi; }
        __syncthreads();
        if (t == 0) {
            for (int w = 1; w < 4; ++w)
                if (redv[w] > bv || (redv[w] == bv && redi[w] < bi)) {
                    bv = redv[w]; bi = redi[w];
                }
            selv[it] = bv;
            seli[it] = bi;
            dv[bi] = -3.4e38f;
        }
        __syncthreads();
    }
    float sum = 0.f;
    for (int it = 0; it < kk; ++it) sum += selv[it];
    float inv = 1.0f / (sum + 1e-8f);
    for (int n = t; n < len; n += 256) {
        float v = 0.0f;
        for (int it = 0; it < kk; ++it)
            if (seli[it] == n) v = selv[it] * inv;
        out[b * 5120 + segOut[sg] + n] = v;
        if (sg == 1) out[b * 5120 + 3072 + n] = v;  // wK == wQ
    }
}

// ---------------------------------------------------------------------------
extern "C" void kernel_launch(void* const* d_in, const int* in_sizes, int n_in,
                              void* d_out, int out_size, void* d_ws, size_t ws_size,
                              hipStream_t stream) {
    (void)in_sizes; (void)n_in; (void)out_size; (void)ws_size;
    const float* x    = (const float*)d_in[0];
    const float* imp  = (const float*)d_in[1];
    const float* W    = (const float*)d_in[2];
    const float* bias = (const float*)d_in[3];
    const float* emb  = (const float*)d_in[4];
    float* out = (float*)d_out;

    // workspace layout (bytes): ~13.6 MB; pc (8MB) time-shares with partials
    char* w = (char*)d_ws;
    __bf16* e_hi  = (__bf16*)w;  w += (size_t)4096 * 64 * 2;      // 512KB
    __bf16* e_lo  = (__bf16*)w;  w += (size_t)4096 * 64 * 2;      // 512KB
    __bf16* h_hi  = (__bf16*)w;  w += (size_t)16384 * 64 * 2;     // 2MB
    __bf16* h_lo  = (__bf16*)w;  w += (size_t)16384 * 64 * 2;     // 2MB
    __bf16* wt_hi = (__bf16*)w;  w += (size_t)64 * 2048 * 2;      // 256KB
    __bf16* wt_lo = (__bf16*)w;  w += (size_t)64 * 2048 * 2;      // 256KB
    float*  pc    = (float*)w;                                    // 8MB shared:
    float*  partials = (float*)w; w += (size_t)4 * 128 * 4096 * 4;
    float*  dacc  = (float*)w;   w += (size_t)4 * 4096 * 4;       // 64KB

    hipLaunchKernelGGL(k_prepe,      dim3(1024), dim3(256), 0, stream, emb, e_hi, e_lo);
    hipLaunchKernelGGL(k_prepw,      dim3(512),  dim3(256), 0, stream, W, wt_hi, wt_lo);
    hipLaunchKernelGGL(k_hgemm_mfma, dim3(512),  dim3(256), 0, stream, x, wt_hi, wt_lo, pc);
    hipLaunchKernelGGL(k_hfix,       dim3(1024), dim3(256), 0, stream, pc, bias, h_hi, h_lo);
    hipLaunchKernelGGL(k_logits,     dim3(256),  dim3(512), 0, stream, h_hi, h_lo,
                       e_hi, e_lo, imp, partials);
    hipLaunchKernelGGL(k_reduce,     dim3(64),   dim3(256), 0, stream, partials, dacc);
    hipLaunchKernelGGL(k_topk,       dim3(12),   dim3(256), 0, stream, dacc, out);
}